// Round 5
// baseline (341.828 us; speedup 1.0000x reference)
//
#include <hip/hip_runtime.h>

// TokenImportanceRouter: scores[b,t] = scale * (hidden[b,t,:]·w_eff[b] + c[b])
//   h̄[b] = mean_t hidden[b,t,:]            pass 1 over hidden (partials, no atomics)
//   k̄[b] = Wk·h̄[b] + bk                    fused reduce+kbar (LDS)
//   w_eff[b] = Wqᵀ·k̄[b];  c[b] = bq·k̄[b]   fused (LDS)
//   scores[b,t] = scale*(hidden[b,t]·w_eff[b] + c[b])   pass 2 over hidden
// 4 kernels, every ws region written before read, fully deterministic.

constexpr int B  = 4;
constexpr int T  = 4096;
constexpr int D  = 2048;
constexpr int DR = 512;
constexpr int NZ = 128;    // T-split for column-sum partials

// ---------------------------------------------------------------- K1: partial column sums
// grid (D/1024, B, NZ), block 256.  Disjoint float4 writes.
__global__ __launch_bounds__(256)
void colsum_part_k(const float* __restrict__ hidden, float* __restrict__ part) {
    const int d4 = blockIdx.x * 256 + threadIdx.x;          // float4 column [0,512)
    const int b  = blockIdx.y;
    const int z  = blockIdx.z;
    const int rows = T / NZ;                                // 32
    const int t0 = z * rows;
    const float4* src = reinterpret_cast<const float4*>(hidden + (size_t)b * T * D);
    float4 acc = make_float4(0.f, 0.f, 0.f, 0.f);
#pragma unroll 8
    for (int t = t0; t < t0 + rows; ++t) {
        float4 v = src[(size_t)t * (D / 4) + d4];
        acc.x += v.x; acc.y += v.y; acc.z += v.z; acc.w += v.w;
    }
    reinterpret_cast<float4*>(part + ((size_t)z * B + b) * D)[d4] = acc;
}

// ---------------------------------------------------------------- K2: fold partials + kbar
// grid (8, B), block 256.  Block: reduce part[*][b][*] -> LDS hsum, then 64 kbar rows.
__global__ __launch_bounds__(256)
void redkbar_k(const float* __restrict__ part, const float* __restrict__ Wk,
               const float* __restrict__ bk, float* __restrict__ kbar) {
    __shared__ float hs[D];                                 // 8 KB
    const int b   = blockIdx.y;
    const int rc  = blockIdx.x;                             // r-chunk of 64
    const int tid = threadIdx.x;
#pragma unroll
    for (int j = 0; j < D / 256; ++j) {                     // 8 d's per thread
        const int d = j * 256 + tid;
        float acc = 0.f;
#pragma unroll 8
        for (int z = 0; z < NZ; ++z) acc += part[((size_t)z * B + b) * D + d];
        hs[d] = acc;
    }
    __syncthreads();
    const int wave = tid >> 6, lane = tid & 63;
    const float4* hs4 = reinterpret_cast<const float4*>(hs);
    for (int j = 0; j < 16; ++j) {                          // 16 rows per wave
        const int r = rc * 64 + wave * 16 + j;
        const float4* wrow = reinterpret_cast<const float4*>(Wk + (size_t)r * D);
        float acc = 0.f;
#pragma unroll
        for (int i = 0; i < D / 4 / 64; ++i) {              // 8
            const int idx = i * 64 + lane;
            float4 wv = wrow[idx];
            float4 hv = hs4[idx];
            acc += wv.x * hv.x + wv.y * hv.y + wv.z * hv.z + wv.w * hv.w;
        }
#pragma unroll
        for (int off = 32; off; off >>= 1) acc += __shfl_down(acc, off);
        if (lane == 0) kbar[b * DR + r] = acc * (1.0f / T) + bk[r];
    }
}

// ---------------------------------------------------------------- K3: w_eff + cterm
// grid (D/256, B), block 256.  kbar[b] staged in LDS; full r-loop per thread.
__global__ __launch_bounds__(256)
void wqeff_k(const float* __restrict__ Wq, const float* __restrict__ bq,
             const float* __restrict__ kbar, float* __restrict__ wqeff,
             float* __restrict__ cterm) {
    __shared__ float kb[DR];                                // 2 KB
    __shared__ float wsum[4];
    const int b   = blockIdx.y;
    const int tid = threadIdx.x;
    kb[tid]       = kbar[b * DR + tid];
    kb[tid + 256] = kbar[b * DR + tid + 256];
    __syncthreads();
    const int d = blockIdx.x * 256 + tid;
    float acc = 0.f;
#pragma unroll 8
    for (int r = 0; r < DR; ++r)
        acc += Wq[(size_t)r * D + d] * kb[r];
    wqeff[(size_t)b * D + d] = acc;

    if (blockIdx.x == 0) {                                  // cterm[b] = bq·k̄[b]
        float a2 = bq[tid] * kb[tid] + bq[tid + 256] * kb[tid + 256];
#pragma unroll
        for (int off = 32; off; off >>= 1) a2 += __shfl_down(a2, off);
        if ((tid & 63) == 0) wsum[tid >> 6] = a2;
        __syncthreads();
        if (tid == 0) cterm[b] = wsum[0] + wsum[1] + wsum[2] + wsum[3];
    }
}

// ---------------------------------------------------------------- K4: scores
// grid (T/4, B), block 256, one t-row per wave.
__global__ __launch_bounds__(256)
void scores_k(const float* __restrict__ hidden, const float* __restrict__ wqeff,
              const float* __restrict__ cterm, float* __restrict__ out) {
    const int b    = blockIdx.y;
    const int wave = threadIdx.x >> 6;
    const int lane = threadIdx.x & 63;
    const int t    = blockIdx.x * 4 + wave;
    const float4* hrow = reinterpret_cast<const float4*>(hidden + ((size_t)b * T + t) * D);
    const float4* w    = reinterpret_cast<const float4*>(wqeff + (size_t)b * D);
    float acc = 0.f;
#pragma unroll
    for (int i = 0; i < D / 4 / 64; ++i) {                  // 8
        const int idx = i * 64 + lane;
        float4 hv = hrow[idx];
        float4 wv = w[idx];
        acc += hv.x * wv.x + hv.y * wv.y + hv.z * wv.z + hv.w * wv.w;
    }
#pragma unroll
    for (int off = 32; off; off >>= 1) acc += __shfl_down(acc, off);
    if (lane == 0) out[(size_t)b * T + t] = (acc + cterm[b]) * 4.41941738241592e-02f; // 512^-0.5
}

extern "C" void kernel_launch(void* const* d_in, const int* in_sizes, int n_in,
                              void* d_out, int out_size, void* d_ws, size_t ws_size,
                              hipStream_t stream) {
    const float* hidden = (const float*)d_in[0];
    const float* Wq     = (const float*)d_in[1];
    const float* bq     = (const float*)d_in[2];
    const float* Wk     = (const float*)d_in[3];
    const float* bk     = (const float*)d_in[4];
    float* out = (float*)d_out;

    // ws (floats): [part NZ*B*D = 1M][kbar B*DR][wqeff B*D][cterm B] — all write-before-read
    float* part  = (float*)d_ws;
    float* kbar  = part + (size_t)NZ * B * D;
    float* wqeff = kbar + B * DR;
    float* cterm = wqeff + B * D;

    dim3 g1(D / 1024, B, NZ);                      // (2, 4, 128) = 1024 blocks
    colsum_part_k<<<g1, 256, 0, stream>>>(hidden, part);

    dim3 g2(8, B);                                 // 32 blocks
    redkbar_k<<<g2, 256, 0, stream>>>(part, Wk, bk, kbar);

    dim3 g3(D / 256, B);                           // (8, 4)
    wqeff_k<<<g3, 256, 0, stream>>>(Wq, bq, kbar, wqeff, cterm);

    dim3 g5(T / 4, B);                             // (1024, 4)
    scores_k<<<g5, 256, 0, stream>>>(hidden, wqeff, cterm, out);
}

// Round 6
// 269.767 us; speedup vs baseline: 1.2671x; 1.2671x over previous
//
#include <hip/hip_runtime.h>

// TokenImportanceRouter: scores[b,t] = scale * (hidden[b,t,:]·w_eff[b] + c[b])
//   h̄[b] = mean_t hidden[b,t,:]            pass 1 over hidden (partials)
//   fold 128 -> 16 partials (wide)          fold_k
//   k̄[b] = Wk·(h̄[b]) + bk                  redkbar_k (fold 16 in LDS + dot)
//   w_eff[b] = Wqᵀ·k̄[b];  c[b] = bq·k̄[b]   wqeff_k
//   scores[b,t] = scale*(hidden[b,t]·w_eff[b] + c[b])   pass 2 over hidden
// 5 kernels, no atomics, every ws region written before read.

constexpr int B   = 4;
constexpr int T   = 4096;
constexpr int D   = 2048;
constexpr int DR  = 512;
constexpr int NZ  = 128;   // stage-1 partials
constexpr int NZ2 = 16;    // stage-2 partials

// ---------------------------------------------------------------- K1: partial column sums
// grid (D/1024, B, NZ), block 256.  Disjoint float4 writes, coalesced reads.
__global__ __launch_bounds__(256)
void colsum_part_k(const float* __restrict__ hidden, float* __restrict__ part) {
    const int d4 = blockIdx.x * 256 + threadIdx.x;          // float4 column [0,512)
    const int b  = blockIdx.y;
    const int z  = blockIdx.z;
    const int rows = T / NZ;                                // 32
    const int t0 = z * rows;
    const float4* src = reinterpret_cast<const float4*>(hidden + (size_t)b * T * D);
    float4 acc = make_float4(0.f, 0.f, 0.f, 0.f);
#pragma unroll 8
    for (int t = t0; t < t0 + rows; ++t) {
        float4 v = src[(size_t)t * (D / 4) + d4];
        acc.x += v.x; acc.y += v.y; acc.z += v.z; acc.w += v.w;
    }
    reinterpret_cast<float4*>(part + ((size_t)z * B + b) * D)[d4] = acc;
}

// ---------------------------------------------------------------- K2: fold 128 -> 16
// grid (D/256, B, NZ2) = 512 blocks, block 256.  Coalesced (d-contiguous) reads.
__global__ __launch_bounds__(256)
void fold_k(const float* __restrict__ part, float* __restrict__ part2) {
    const int d  = blockIdx.x * 256 + threadIdx.x;
    const int b  = blockIdx.y;
    const int zc = blockIdx.z;
    float acc = 0.f;
#pragma unroll
    for (int z = zc * (NZ / NZ2); z < (zc + 1) * (NZ / NZ2); ++z)   // 8
        acc += part[((size_t)z * B + b) * D + d];
    part2[((size_t)zc * B + b) * D + d] = acc;
}

// ---------------------------------------------------------------- K3: fold 16 + kbar
// grid (DR/16, B) = 128 blocks, block 256 (4 waves, 4 rows each).
__global__ __launch_bounds__(256)
void redkbar_k(const float* __restrict__ part2, const float* __restrict__ Wk,
               const float* __restrict__ bk, float* __restrict__ kbar) {
    __shared__ float hs[D];                                 // 8 KB
    const int b   = blockIdx.y;
    const int tid = threadIdx.x;
#pragma unroll
    for (int j = 0; j < D / 256; ++j) {                     // 8 d's per thread
        const int d = j * 256 + tid;
        float acc = 0.f;
#pragma unroll
        for (int zc = 0; zc < NZ2; ++zc)                    // 16, L2/L3-hot
            acc += part2[((size_t)zc * B + b) * D + d];
        hs[d] = acc;
    }
    __syncthreads();
    const int wave = tid >> 6, lane = tid & 63;
    const float4* hs4 = reinterpret_cast<const float4*>(hs);
#pragma unroll
    for (int j = 0; j < 4; ++j) {                           // 4 rows per wave
        const int r = blockIdx.x * 16 + wave * 4 + j;
        const float4* wrow = reinterpret_cast<const float4*>(Wk + (size_t)r * D);
        float acc = 0.f;
#pragma unroll
        for (int i = 0; i < D / 4 / 64; ++i) {              // 8
            const int idx = i * 64 + lane;
            float4 wv = wrow[idx];
            float4 hv = hs4[idx];
            acc += wv.x * hv.x + wv.y * hv.y + wv.z * hv.z + wv.w * hv.w;
        }
#pragma unroll
        for (int off = 32; off; off >>= 1) acc += __shfl_down(acc, off);
        if (lane == 0) kbar[b * DR + r] = acc * (1.0f / T) + bk[r];
    }
}

// ---------------------------------------------------------------- K4: w_eff + cterm
// grid (D/256, B), block 256.  kbar[b] staged in LDS; full r-loop per thread.
__global__ __launch_bounds__(256)
void wqeff_k(const float* __restrict__ Wq, const float* __restrict__ bq,
             const float* __restrict__ kbar, float* __restrict__ wqeff,
             float* __restrict__ cterm) {
    __shared__ float kb[DR];                                // 2 KB
    __shared__ float wsum[4];
    const int b   = blockIdx.y;
    const int tid = threadIdx.x;
    kb[tid]       = kbar[b * DR + tid];
    kb[tid + 256] = kbar[b * DR + tid + 256];
    __syncthreads();
    const int d = blockIdx.x * 256 + tid;
    float acc = 0.f;
#pragma unroll 8
    for (int r = 0; r < DR; ++r)
        acc += Wq[(size_t)r * D + d] * kb[r];
    wqeff[(size_t)b * D + d] = acc;

    if (blockIdx.x == 0) {                                  // cterm[b] = bq·k̄[b]
        float a2 = bq[tid] * kb[tid] + bq[tid + 256] * kb[tid + 256];
#pragma unroll
        for (int off = 32; off; off >>= 1) a2 += __shfl_down(a2, off);
        if ((tid & 63) == 0) wsum[tid >> 6] = a2;
        __syncthreads();
        if (tid == 0) cterm[b] = wsum[0] + wsum[1] + wsum[2] + wsum[3];
    }
}

// ---------------------------------------------------------------- K5: scores
// grid (T/4, B), block 256, one t-row per wave.
__global__ __launch_bounds__(256)
void scores_k(const float* __restrict__ hidden, const float* __restrict__ wqeff,
              const float* __restrict__ cterm, float* __restrict__ out) {
    const int b    = blockIdx.y;
    const int wave = threadIdx.x >> 6;
    const int lane = threadIdx.x & 63;
    const int t    = blockIdx.x * 4 + wave;
    const float4* hrow = reinterpret_cast<const float4*>(hidden + ((size_t)b * T + t) * D);
    const float4* w    = reinterpret_cast<const float4*>(wqeff + (size_t)b * D);
    float acc = 0.f;
#pragma unroll
    for (int i = 0; i < D / 4 / 64; ++i) {                  // 8
        const int idx = i * 64 + lane;
        float4 hv = hrow[idx];
        float4 wv = w[idx];
        acc += hv.x * wv.x + hv.y * wv.y + hv.z * wv.z + hv.w * wv.w;
    }
#pragma unroll
    for (int off = 32; off; off >>= 1) acc += __shfl_down(acc, off);
    if (lane == 0) out[(size_t)b * T + t] = (acc + cterm[b]) * 4.41941738241592e-02f; // 512^-0.5
}

extern "C" void kernel_launch(void* const* d_in, const int* in_sizes, int n_in,
                              void* d_out, int out_size, void* d_ws, size_t ws_size,
                              hipStream_t stream) {
    const float* hidden = (const float*)d_in[0];
    const float* Wq     = (const float*)d_in[1];
    const float* bq     = (const float*)d_in[2];
    const float* Wk     = (const float*)d_in[3];
    const float* bk     = (const float*)d_in[4];
    float* out = (float*)d_out;

    // ws (floats): [part NZ*B*D][part2 NZ2*B*D][kbar B*DR][wqeff B*D][cterm B]
    float* part  = (float*)d_ws;
    float* part2 = part + (size_t)NZ * B * D;
    float* kbar  = part2 + (size_t)NZ2 * B * D;
    float* wqeff = kbar + B * DR;
    float* cterm = wqeff + B * D;

    dim3 g1(D / 1024, B, NZ);                      // (2, 4, 128) = 1024 blocks
    colsum_part_k<<<g1, 256, 0, stream>>>(hidden, part);

    dim3 g2(D / 256, B, NZ2);                      // (8, 4, 16) = 512 blocks
    fold_k<<<g2, 256, 0, stream>>>(part, part2);

    dim3 g3(DR / 16, B);                           // (32, 4) = 128 blocks
    redkbar_k<<<g3, 256, 0, stream>>>(part2, Wk, bk, kbar);

    dim3 g4(D / 256, B);                           // (8, 4)
    wqeff_k<<<g4, 256, 0, stream>>>(Wq, bq, kbar, wqeff, cterm);

    dim3 g5(T / 4, B);                             // (1024, 4)
    scores_k<<<g5, 256, 0, stream>>>(hidden, wqeff, cterm, out);
}